// Round 3
// baseline (318.887 us; speedup 1.0000x reference)
//
#include <hip/hip_runtime.h>
#include <cstdint>
#include <cstddef>

typedef unsigned short u16;
typedef unsigned int u32;
typedef __attribute__((ext_vector_type(8))) short short8;
typedef __attribute__((ext_vector_type(4))) float f32x4;

__device__ __forceinline__ float bf2f(u16 v) { return __uint_as_float((u32)v << 16); }
__device__ __forceinline__ u16 f2bf(float f) {
    u32 u = __float_as_uint(f);
    u = (u + 0x7fffu + ((u >> 16) & 1u)) >> 16;   // RNE, finite values only
    return (u16)u;
}

// async global->LDS, 16 B/lane; LDS dest must be wave-uniform base + lane*16
#define GLD16(g, l) __builtin_amdgcn_global_load_lds( \
    (const __attribute__((address_space(1))) void*)(g), \
    (__attribute__((address_space(3))) void*)(l), 16, 0, 0)

// ------------------------------------------------------------------
// Kernel 0: dtype sniffer (flag=1 -> fp32 inputs).
// ------------------------------------------------------------------
__global__ void detect_kernel(const u16* __restrict__ x, int* __restrict__ flag) {
    int cnt = 0;
    for (int i = threadIdx.x; i < 256; i += 64) {
        const int e = (x[2 * i] >> 7) & 0xFF;
        cnt += (e >= 96 && e <= 135) ? 1 : 0;
    }
    #pragma unroll
    for (int o = 32; o; o >>= 1) cnt += __shfl_down(cnt, o, 64);
    if (threadIdx.x == 0) *flag = (cnt < 128) ? 1 : 0;
}

// ------------------------------------------------------------------
// Kernel 1: W [384,768] -> bf16.
// ------------------------------------------------------------------
__global__ void wconv_kernel(const void* __restrict__ w, u16* __restrict__ wbf,
                             const int* __restrict__ flag) {
    const int i = blockIdx.x * 256 + threadIdx.x;
    if (i >= 384 * 768) return;
    if (*flag) wbf[i] = f2bf(((const float*)w)[i]);
    else       wbf[i] = ((const u16*)w)[i];
}

// ------------------------------------------------------------------
// Kernel 2: x_j stencil, pixel-major LDS [3136][8ch]. (unchanged)
// ------------------------------------------------------------------
__global__ __launch_bounds__(256) void xj_kernel(const void* __restrict__ xin,
                                                 u16* __restrict__ xc,
                                                 const int* __restrict__ flag) {
    const int cg = blockIdx.x, b = blockIdx.y;
    const int fp = *flag;
    __shared__ __align__(16) u16 pl[3136][8];
    const size_t plane0 = ((size_t)b * 384 + (size_t)cg * 8) * 3136;

    if (fp) {
        const float* xb = (const float*)xin + plane0;
        for (int g = threadIdx.x; g < 784; g += 256) {
            const int p = g * 4;
            float vv[8][4];
            #pragma unroll
            for (int c = 0; c < 8; ++c) {
                const float4 t = *(const float4*)(xb + (size_t)c * 3136 + p);
                vv[c][0] = t.x; vv[c][1] = t.y; vv[c][2] = t.z; vv[c][3] = t.w;
            }
            #pragma unroll
            for (int i = 0; i < 4; ++i) {
                u32 q[4];
                #pragma unroll
                for (int cc = 0; cc < 4; ++cc)
                    q[cc] = (u32)f2bf(vv[cc * 2][i]) | ((u32)f2bf(vv[cc * 2 + 1][i]) << 16);
                *(uint4*)&pl[p + i][0] = make_uint4(q[0], q[1], q[2], q[3]);
            }
        }
    } else {
        const u16* xb = (const u16*)xin + plane0;
        for (int g = threadIdx.x; g < 784; g += 256) {
            const int p = g * 4;
            u32 rc[8][2];
            #pragma unroll
            for (int c = 0; c < 8; ++c) {
                const uint2 t = *(const uint2*)(xb + (size_t)c * 3136 + p);
                rc[c][0] = t.x; rc[c][1] = t.y;
            }
            #pragma unroll
            for (int i = 0; i < 4; ++i) {
                const int d = i >> 1, sh = (i & 1) * 16;
                u32 q[4];
                #pragma unroll
                for (int cc = 0; cc < 4; ++cc) {
                    const u32 lo = (rc[cc * 2][d] >> sh) & 0xFFFFu;
                    const u32 hi = (rc[cc * 2 + 1][d] >> sh) & 0xFFFFu;
                    q[cc] = lo | (hi << 16);
                }
                *(uint4*)&pl[p + i][0] = make_uint4(q[0], q[1], q[2], q[3]);
            }
        }
    }
    __syncthreads();

    for (int p = threadIdx.x; p < 3136; p += 256) {
        const int h = p / 56, w = p - h * 56;
        int off[20];
        const int S[5] = {1, 3, 7, 15, 31};
        #pragma unroll
        for (int si = 0; si < 5; ++si) {
            const int s = S[si];
            int hp = h + s; if (hp >= 56) hp -= 56;
            int hm = h - s; if (hm < 0)   hm += 56;
            int wp = w + s; if (wp >= 56) wp -= 56;
            int wm = w - s; if (wm < 0)   wm += 56;
            off[si * 4 + 0] = hp * 56 + w;
            off[si * 4 + 1] = hm * 56 + w;
            off[si * 4 + 2] = h * 56 + wp;
            off[si * 4 + 3] = h * 56 + wm;
        }
        const uint4 self = *(const uint4*)&pl[p][0];
        const u32 sw[4] = {self.x, self.y, self.z, self.w};
        float xv[8], mn[8];
        #pragma unroll
        for (int c2 = 0; c2 < 4; ++c2) {
            xv[c2 * 2]     = __uint_as_float(sw[c2] << 16);
            xv[c2 * 2 + 1] = __uint_as_float(sw[c2] & 0xFFFF0000u);
            mn[c2 * 2] = xv[c2 * 2]; mn[c2 * 2 + 1] = xv[c2 * 2 + 1];
        }
        #pragma unroll
        for (int k = 0; k < 20; k += 2) {
            const uint4 na = *(const uint4*)&pl[off[k]][0];
            const uint4 nb = *(const uint4*)&pl[off[k + 1]][0];
            const u32 aw[4] = {na.x, na.y, na.z, na.w};
            const u32 bw[4] = {nb.x, nb.y, nb.z, nb.w};
            #pragma unroll
            for (int c2 = 0; c2 < 4; ++c2) {
                mn[c2 * 2]     = fminf(fminf(__uint_as_float(aw[c2] << 16),
                                             __uint_as_float(bw[c2] << 16)), mn[c2 * 2]);
                mn[c2 * 2 + 1] = fminf(fminf(__uint_as_float(aw[c2] & 0xFFFF0000u),
                                             __uint_as_float(bw[c2] & 0xFFFF0000u)), mn[c2 * 2 + 1]);
            }
        }
        u32 jq[4];
        #pragma unroll
        for (int c2 = 0; c2 < 4; ++c2)
            jq[c2] = (u32)f2bf(xv[c2 * 2] - mn[c2 * 2]) |
                     ((u32)f2bf(xv[c2 * 2 + 1] - mn[c2 * 2 + 1]) << 16);
        u16* px = xc + ((((size_t)b * 96) + cg) * 3136 + p) * 8;
        u16* pj = xc + ((((size_t)b * 96) + 48 + cg) * 3136 + p) * 8;
        *(uint4*)px = self;
        *(uint4*)pj = make_uint4(jq[0], jq[1], jq[2], jq[3]);
    }
}

// ------------------------------------------------------------------
// Kernel 3: Y = Wbf[384,768] @ Xc[768,50176] + BN + exact GELU.
// v4: TLP-first redesign. M=384 x N=64 per block (B staged once), 512
// threads = 8 waves in a 4M x 2N grid; each wave owns 96x32 (6x2 frags).
// Per-wave state fits 128 unified regs -> 2 blocks/CU (16 waves)
// [__launch_bounds__(512,4)]. A-fragments: s-step-granular ping-pong ring
// (2x6 short8), issued one s-step early so the vmcnt FIFO never forces an
// early drain of the B stage (A-use waits leave stage loads in flight).
// A addressing: 6 fixed row pointers + compile-time t*64B immediates
// (zero VALU in the loop). Counted vmcnt(8)/(6) at phase ends; no setprio
// (lockstep regime); no end-of-loop barrier (epilogue T is separate LDS).
// grid 784, block 512.
// ------------------------------------------------------------------
__global__ __launch_bounds__(512, 4) void gemm_kernel(
        const u16* __restrict__ xc, const u16* __restrict__ Wt,
        const void* __restrict__ cb, const void* __restrict__ bsc,
        const void* __restrict__ bbi, const void* __restrict__ bme,
        const void* __restrict__ bva, void* __restrict__ outp,
        const int* __restrict__ flag) {
    const int ntile = blockIdx.x;             // 0..783
    const int fp = *flag;
    __shared__ __align__(16) u16 Bs[2][16 * 64 * 8];   // 2 x 16 KB
    __shared__ __align__(16) float T[8][16][36];       // 18432 B epilogue
    __shared__ float2 PB[384];

    const int tid = threadIdx.x;
    if (tid < 384) {
        float vsc, vva, vcb, vme, vbi;
        if (fp) {
            vsc = ((const float*)bsc)[tid]; vva = ((const float*)bva)[tid];
            vcb = ((const float*)cb)[tid];  vme = ((const float*)bme)[tid];
            vbi = ((const float*)bbi)[tid];
        } else {
            vsc = bf2f(((const u16*)bsc)[tid]); vva = bf2f(((const u16*)bva)[tid]);
            vcb = bf2f(((const u16*)cb)[tid]);  vme = bf2f(((const u16*)bme)[tid]);
            vbi = bf2f(((const u16*)bbi)[tid]);
        }
        const float seff = vsc * rsqrtf(vva + 1e-5f);
        PB[tid] = make_float2(seff, (vcb - vme) * seff + vbi);
    }

    const int lane = tid & 63, wv = tid >> 6;
    const int quad = lane >> 4, l16 = lane & 15;
    const int wv_m = wv >> 1, wv_n = wv & 1;      // 4M x 2N wave grid
    const int bb  = ntile / 49;
    const int hw0 = (ntile - bb * 49) * 64;

    // B staging: phase q covers groups q*16..+16; 1024 16B-chunks, 2/thread.
    const u16* bgp[2]; int bofs[2];
    #pragma unroll
    for (int i = 0; i < 2; ++i) {
        const int idx = i * 512 + tid;        // 0..1023
        const int gg = idx >> 6, n = idx & 63;
        bgp[i]  = xc + (((size_t)bb * 96 + gg) * 3136 + hw0 + n) * 8;
        bofs[i] = idx * 8;
    }
    #define STAGE(q) { \
        u16* dst = &Bs[(q) & 1][0]; \
        GLD16(bgp[0] + (size_t)(q) * 16 * 3136 * 8, dst + bofs[0]); \
        GLD16(bgp[1] + (size_t)(q) * 16 * 3136 * 8, dst + bofs[1]); }

    // A row pointers: row = wv_m*96 + j*16 + l16; k-offset via imm t*64B.
    const u16* arow[6];
    #pragma unroll
    for (int j = 0; j < 6; ++j)
        arow[j] = Wt + (size_t)(wv_m * 96 + j * 16 + l16) * 768 + quad * 8;

    #define LOADA(dst, t) { \
        _Pragma("unroll") \
        for (int j = 0; j < 6; ++j) \
            dst[j] = *(const short8*)(arow[j] + (t) * 32); }

    f32x4 acc[6][2];
    #pragma unroll
    for (int j = 0; j < 6; ++j) {
        acc[j][0] = {0.f, 0.f, 0.f, 0.f};
        acc[j][1] = {0.f, 0.f, 0.f, 0.f};
    }

    short8 afP[6], afQ[6];

    // Prologue: A(t=0)->afP, stage(0), stage(1).
    // FIFO: [afP 6, st0 2, st1 2]; vmcnt(2) drains afP+st0, keeps st1 in flight.
    LOADA(afP, 0);
    STAGE(0);
    STAGE(1);
    asm volatile("s_waitcnt vmcnt(2) lgkmcnt(0)" ::: "memory");
    __builtin_amdgcn_s_barrier();

    // s-step: prefetch A(t+1) into the other ring slot (issued BEFORE the
    // MFMAs and before any younger STAGE -> A-use waits never drain stage),
    // read 2 B-frags from LDS, 12 MFMA.
    #define SSTEP(q, s, CUR, NXT) { \
        if ((q) * 4 + (s) + 1 < 24) LOADA(NXT, (q) * 4 + (s) + 1); \
        short8 bfv[2]; \
        _Pragma("unroll") \
        for (int in = 0; in < 2; ++in) \
            bfv[in] = *(const short8*)(&Bs[(q) & 1][0] + \
                (((s) * 4 + quad) * 64 + wv_n * 32 + in * 16 + l16) * 8); \
        _Pragma("unroll") \
        for (int j = 0; j < 6; ++j) { \
            acc[j][0] = __builtin_amdgcn_mfma_f32_16x16x32_bf16(CUR[j], bfv[0], acc[j][0], 0, 0, 0); \
            acc[j][1] = __builtin_amdgcn_mfma_f32_16x16x32_bf16(CUR[j], bfv[1], acc[j][1], 0, 0, 0); } }

    // Phase q: 4 s-steps; barrier (buf[q&1] free); stage(q+2) into buf[q&1];
    // counted wait for stage(q+1) [outstanding: af(next)=6 + stage(q+2)=2];
    // barrier. Never vmcnt(0) in the loop.
    #define PHASE(q) { \
        SSTEP(q, 0, afP, afQ); \
        SSTEP(q, 1, afQ, afP); \
        SSTEP(q, 2, afP, afQ); \
        SSTEP(q, 3, afQ, afP); \
        if ((q) < 5) { \
            __builtin_amdgcn_s_barrier(); \
            if ((q) < 4) STAGE((q) + 2); \
            if ((q) <= 3) { asm volatile("s_waitcnt vmcnt(8)" ::: "memory"); } \
            else          { asm volatile("s_waitcnt vmcnt(6)" ::: "memory"); } \
            __builtin_amdgcn_s_barrier(); } }

    PHASE(0); PHASE(1); PHASE(2); PHASE(3); PHASE(4); PHASE(5);

    // --- epilogue: BN + exact GELU, per-wave LDS transpose, coalesced stores.
    // T is disjoint from Bs: no barrier needed; lgkmcnt(0) is wave-local.
    const size_t obase = (size_t)bb * 384 * 3136 + hw0 + wv_n * 32;
    #pragma unroll
    for (int j = 0; j < 6; ++j) {
        #pragma unroll
        for (int r = 0; r < 4; ++r) {
            const int rl = quad * 4 + r;
            const float2 sb = PB[wv_m * 96 + j * 16 + rl];
            #pragma unroll
            for (int in = 0; in < 2; ++in) {
                float v = acc[j][in][r] * sb.x + sb.y;
                v = 0.5f * v * (1.0f + erff(v * 0.70710678118654752f));
                T[wv][rl][in * 16 + l16] = v;
            }
        }
        asm volatile("s_waitcnt lgkmcnt(0)" ::: "memory");
        #pragma unroll
        for (int it = 0; it < 2; ++it) {
            const int flat = it * 256 + lane * 4;   // 0..511
            const int row = flat >> 5, col = flat & 31;
            const float4 vv = *(const float4*)&T[wv][row][col];
            const size_t oi = obase + (size_t)(wv_m * 96 + j * 16 + row) * 3136 + col;
            if (fp) {
                *(float4*)((float*)outp + oi) = vv;
            } else {
                const u32 a = (u32)f2bf(vv.x) | ((u32)f2bf(vv.y) << 16);
                const u32 b2 = (u32)f2bf(vv.z) | ((u32)f2bf(vv.w) << 16);
                *(uint2*)((u16*)outp + oi) = make_uint2(a, b2);
            }
        }
        asm volatile("s_waitcnt lgkmcnt(0)" ::: "memory");
    }
    #undef PHASE
    #undef SSTEP
    #undef LOADA
    #undef STAGE
}

extern "C" void kernel_launch(void* const* d_in, const int* in_sizes, int n_in,
                              void* d_out, int out_size, void* d_ws, size_t ws_size,
                              hipStream_t stream) {
    const void* x   = d_in[0];
    const void* w   = d_in[1];
    const void* cbp = d_in[2];
    const void* bsc = d_in[3];
    const void* bbi = d_in[4];
    const void* bme = d_in[5];
    const void* bva = d_in[6];

    int* flag = (int*)d_ws;
    u16* xc   = (u16*)((char*)d_ws + 64);            // 77,070,336 B
    u16* wbf  = xc + (size_t)16 * 96 * 3136 * 8;     // 589,824 B

    detect_kernel<<<1, 64, 0, stream>>>((const u16*)x, flag);
    wconv_kernel<<<1152, 256, 0, stream>>>(w, wbf, flag);
    xj_kernel<<<dim3(48, 16), 256, 0, stream>>>(x, xc, flag);
    gemm_kernel<<<784, 512, 0, stream>>>(xc, wbf, cbp, bsc, bbi, bme, bva,
                                         d_out, flag);
}

// Round 4
// 303.398 us; speedup vs baseline: 1.0511x; 1.0511x over previous
//
#include <hip/hip_runtime.h>
#include <cstdint>
#include <cstddef>

typedef unsigned short u16;
typedef unsigned int u32;
typedef __attribute__((ext_vector_type(8))) short short8;
typedef __attribute__((ext_vector_type(4))) float f32x4;

__device__ __forceinline__ float bf2f(u16 v) { return __uint_as_float((u32)v << 16); }
__device__ __forceinline__ u16 f2bf(float f) {
    u32 u = __float_as_uint(f);
    u = (u + 0x7fffu + ((u >> 16) & 1u)) >> 16;   // RNE, finite values only
    return (u16)u;
}

// async global->LDS, 16 B/lane; LDS dest must be wave-uniform base + lane*16
#define GLD16(g, l) __builtin_amdgcn_global_load_lds( \
    (const __attribute__((address_space(1))) void*)(g), \
    (__attribute__((address_space(3))) void*)(l), 16, 0, 0)

// ------------------------------------------------------------------
// Kernel 0: dtype sniffer (flag=1 -> fp32 inputs).
// ------------------------------------------------------------------
__global__ void detect_kernel(const u16* __restrict__ x, int* __restrict__ flag) {
    int cnt = 0;
    for (int i = threadIdx.x; i < 256; i += 64) {
        const int e = (x[2 * i] >> 7) & 0xFF;
        cnt += (e >= 96 && e <= 135) ? 1 : 0;
    }
    #pragma unroll
    for (int o = 32; o; o >>= 1) cnt += __shfl_down(cnt, o, 64);
    if (threadIdx.x == 0) *flag = (cnt < 128) ? 1 : 0;
}

// ------------------------------------------------------------------
// Kernel 1: W [384,768] -> bf16.
// ------------------------------------------------------------------
__global__ void wconv_kernel(const void* __restrict__ w, u16* __restrict__ wbf,
                             const int* __restrict__ flag) {
    const int i = blockIdx.x * 256 + threadIdx.x;
    if (i >= 384 * 768) return;
    if (*flag) wbf[i] = f2bf(((const float*)w)[i]);
    else       wbf[i] = ((const u16*)w)[i];
}

// ------------------------------------------------------------------
// Kernel 2: x_j stencil, pixel-major LDS [3136][8ch]. (unchanged)
// ------------------------------------------------------------------
__global__ __launch_bounds__(256) void xj_kernel(const void* __restrict__ xin,
                                                 u16* __restrict__ xc,
                                                 const int* __restrict__ flag) {
    const int cg = blockIdx.x, b = blockIdx.y;
    const int fp = *flag;
    __shared__ __align__(16) u16 pl[3136][8];
    const size_t plane0 = ((size_t)b * 384 + (size_t)cg * 8) * 3136;

    if (fp) {
        const float* xb = (const float*)xin + plane0;
        for (int g = threadIdx.x; g < 784; g += 256) {
            const int p = g * 4;
            float vv[8][4];
            #pragma unroll
            for (int c = 0; c < 8; ++c) {
                const float4 t = *(const float4*)(xb + (size_t)c * 3136 + p);
                vv[c][0] = t.x; vv[c][1] = t.y; vv[c][2] = t.z; vv[c][3] = t.w;
            }
            #pragma unroll
            for (int i = 0; i < 4; ++i) {
                u32 q[4];
                #pragma unroll
                for (int cc = 0; cc < 4; ++cc)
                    q[cc] = (u32)f2bf(vv[cc * 2][i]) | ((u32)f2bf(vv[cc * 2 + 1][i]) << 16);
                *(uint4*)&pl[p + i][0] = make_uint4(q[0], q[1], q[2], q[3]);
            }
        }
    } else {
        const u16* xb = (const u16*)xin + plane0;
        for (int g = threadIdx.x; g < 784; g += 256) {
            const int p = g * 4;
            u32 rc[8][2];
            #pragma unroll
            for (int c = 0; c < 8; ++c) {
                const uint2 t = *(const uint2*)(xb + (size_t)c * 3136 + p);
                rc[c][0] = t.x; rc[c][1] = t.y;
            }
            #pragma unroll
            for (int i = 0; i < 4; ++i) {
                const int d = i >> 1, sh = (i & 1) * 16;
                u32 q[4];
                #pragma unroll
                for (int cc = 0; cc < 4; ++cc) {
                    const u32 lo = (rc[cc * 2][d] >> sh) & 0xFFFFu;
                    const u32 hi = (rc[cc * 2 + 1][d] >> sh) & 0xFFFFu;
                    q[cc] = lo | (hi << 16);
                }
                *(uint4*)&pl[p + i][0] = make_uint4(q[0], q[1], q[2], q[3]);
            }
        }
    }
    __syncthreads();

    for (int p = threadIdx.x; p < 3136; p += 256) {
        const int h = p / 56, w = p - h * 56;
        int off[20];
        const int S[5] = {1, 3, 7, 15, 31};
        #pragma unroll
        for (int si = 0; si < 5; ++si) {
            const int s = S[si];
            int hp = h + s; if (hp >= 56) hp -= 56;
            int hm = h - s; if (hm < 0)   hm += 56;
            int wp = w + s; if (wp >= 56) wp -= 56;
            int wm = w - s; if (wm < 0)   wm += 56;
            off[si * 4 + 0] = hp * 56 + w;
            off[si * 4 + 1] = hm * 56 + w;
            off[si * 4 + 2] = h * 56 + wp;
            off[si * 4 + 3] = h * 56 + wm;
        }
        const uint4 self = *(const uint4*)&pl[p][0];
        const u32 sw[4] = {self.x, self.y, self.z, self.w};
        float xv[8], mn[8];
        #pragma unroll
        for (int c2 = 0; c2 < 4; ++c2) {
            xv[c2 * 2]     = __uint_as_float(sw[c2] << 16);
            xv[c2 * 2 + 1] = __uint_as_float(sw[c2] & 0xFFFF0000u);
            mn[c2 * 2] = xv[c2 * 2]; mn[c2 * 2 + 1] = xv[c2 * 2 + 1];
        }
        #pragma unroll
        for (int k = 0; k < 20; k += 2) {
            const uint4 na = *(const uint4*)&pl[off[k]][0];
            const uint4 nb = *(const uint4*)&pl[off[k + 1]][0];
            const u32 aw[4] = {na.x, na.y, na.z, na.w};
            const u32 bw[4] = {nb.x, nb.y, nb.z, nb.w};
            #pragma unroll
            for (int c2 = 0; c2 < 4; ++c2) {
                mn[c2 * 2]     = fminf(fminf(__uint_as_float(aw[c2] << 16),
                                             __uint_as_float(bw[c2] << 16)), mn[c2 * 2]);
                mn[c2 * 2 + 1] = fminf(fminf(__uint_as_float(aw[c2] & 0xFFFF0000u),
                                             __uint_as_float(bw[c2] & 0xFFFF0000u)), mn[c2 * 2 + 1]);
            }
        }
        u32 jq[4];
        #pragma unroll
        for (int c2 = 0; c2 < 4; ++c2)
            jq[c2] = (u32)f2bf(xv[c2 * 2] - mn[c2 * 2]) |
                     ((u32)f2bf(xv[c2 * 2 + 1] - mn[c2 * 2 + 1]) << 16);
        u16* px = xc + ((((size_t)b * 96) + cg) * 3136 + p) * 8;
        u16* pj = xc + ((((size_t)b * 96) + 48 + cg) * 3136 + p) * 8;
        *(uint4*)px = self;
        *(uint4*)pj = make_uint4(jq[0], jq[1], jq[2], jq[3]);
    }
}

// ------------------------------------------------------------------
// Kernel 3: Y = Wbf[384,768] @ Xc[768,50176] + BN + exact GELU.
// v5: SINGLE-STAGE design -- the per-phase barrier pipeline (v0/v3/v4)
// spent 15-40k cycles/phase on convoys; eliminated wholesale.
// Per block: M=384 x N=32, full K=768. Stage the ENTIRE B tile (48 KB,
// 12 GLD16/thread in one burst -> deep MLP, HBM can saturate), ONE
// __syncthreads, then 24 MFMA s-steps with NO barriers and a clean
// per-wave vmcnt FIFO (only the 3-deep A-ring is ever outstanding, so
// compiler A-waits never drain anything else). A-ring: 2-s-step
// lookahead (~2x L2 latency) -> no per-step stall. 4 waves, each 96x32
// (6x2 frags). LDS 60 KB < 64 KB static limit -> 2 blocks/CU: one
// block's fill+epilogue overlaps the other's compute. grid 1568.
// ------------------------------------------------------------------
__global__ __launch_bounds__(256, 2) void gemm_kernel(
        const u16* __restrict__ xc, const u16* __restrict__ Wt,
        const void* __restrict__ cb, const void* __restrict__ bsc,
        const void* __restrict__ bbi, const void* __restrict__ bme,
        const void* __restrict__ bva, void* __restrict__ outp,
        const int* __restrict__ flag) {
    const int fp = *flag;
    __shared__ __align__(16) u16 Bs[96][32][8];       // 49152 B
    __shared__ __align__(16) float T[4][16][36];      // 9216 B
    __shared__ float2 PB[384];                        // 3072 B

    const int tid = threadIdx.x;
    for (int o = tid; o < 384; o += 256) {
        float vsc, vva, vcb, vme, vbi;
        if (fp) {
            vsc = ((const float*)bsc)[o]; vva = ((const float*)bva)[o];
            vcb = ((const float*)cb)[o];  vme = ((const float*)bme)[o];
            vbi = ((const float*)bbi)[o];
        } else {
            vsc = bf2f(((const u16*)bsc)[o]); vva = bf2f(((const u16*)bva)[o]);
            vcb = bf2f(((const u16*)cb)[o]);  vme = bf2f(((const u16*)bme)[o]);
            vbi = bf2f(((const u16*)bbi)[o]);
        }
        const float seff = vsc * rsqrtf(vva + 1e-5f);
        PB[o] = make_float2(seff, (vcb - vme) * seff + vbi);
    }

    const int lane = tid & 63, wv = tid >> 6;
    const int quad = lane >> 4, l16 = lane & 15;
    const int bb  = blockIdx.x / 98;                  // image index 0..15
    const int hw0 = (blockIdx.x - bb * 98) * 32;      // pixel base 0..3104

    // A row pointers: row = wv*96 + j*16 + l16; k-offset via imm t*64B.
    const u16* arow[6];
    #pragma unroll
    for (int j = 0; j < 6; ++j)
        arow[j] = Wt + (size_t)(wv * 96 + j * 16 + l16) * 768 + quad * 8;

    #define LOADA(dst, t) { \
        _Pragma("unroll") \
        for (int j = 0; j < 6; ++j) \
            dst[j] = *(const short8*)(arow[j] + (t) * 32); }

    f32x4 acc[6][2];
    #pragma unroll
    for (int j = 0; j < 6; ++j) {
        acc[j][0] = {0.f, 0.f, 0.f, 0.f};
        acc[j][1] = {0.f, 0.f, 0.f, 0.f};
    }

    short8 sA[6], sB[6], sC[6];

    // ---- prologue: preload A(0),A(1); burst-stage whole B tile; one sync.
    LOADA(sA, 0);
    LOADA(sB, 1);
    {
        const u16* xbase = xc + ((size_t)bb * 96 * 3136 + hw0) * 8;
        u16* ldsbase = &Bs[0][0][0];
        #pragma unroll
        for (int i = 0; i < 12; ++i) {
            const int idx = i * 256 + tid;            // 0..3071 chunks of 16B
            const int gg = idx >> 5, n = idx & 31;    // group, pixel
            GLD16(xbase + ((size_t)gg * 3136 + n) * 8, ldsbase + idx * 8);
        }
    }
    __syncthreads();

    // ---- 24 s-steps, no barriers. CUR = slot[t%3]; prefetch A(t+2) into
    // slot[(t+2)%3] (2-step lookahead: A-wait drains only older A-loads).
    #define SSTEP(t, CUR, NXT) { \
        if ((t) + 2 < 24) LOADA(NXT, (t) + 2); \
        const short8 bfv0 = *(const short8*)&Bs[(t) * 4 + quad][l16][0]; \
        const short8 bfv1 = *(const short8*)&Bs[(t) * 4 + quad][16 + l16][0]; \
        __builtin_amdgcn_s_setprio(1); \
        _Pragma("unroll") \
        for (int j = 0; j < 6; ++j) { \
            acc[j][0] = __builtin_amdgcn_mfma_f32_16x16x32_bf16(CUR[j], bfv0, acc[j][0], 0, 0, 0); \
            acc[j][1] = __builtin_amdgcn_mfma_f32_16x16x32_bf16(CUR[j], bfv1, acc[j][1], 0, 0, 0); } \
        __builtin_amdgcn_s_setprio(0); }

    #define TRIP(t) { SSTEP(t, sA, sC); SSTEP((t) + 1, sB, sA); SSTEP((t) + 2, sC, sB); }

    TRIP(0); TRIP(3); TRIP(6); TRIP(9); TRIP(12); TRIP(15); TRIP(18); TRIP(21);

    // ---- epilogue: BN + exact GELU, per-wave LDS transpose, coalesced
    // stores. T is per-wave disjoint and separate from Bs: no barriers.
    const size_t obase = (size_t)bb * 384 * 3136 + hw0;
    #pragma unroll
    for (int j = 0; j < 6; ++j) {
        #pragma unroll
        for (int r = 0; r < 4; ++r) {
            const int rl = quad * 4 + r;
            const float2 sb = PB[wv * 96 + j * 16 + rl];
            #pragma unroll
            for (int in = 0; in < 2; ++in) {
                float v = acc[j][in][r] * sb.x + sb.y;
                v = 0.5f * v * (1.0f + erff(v * 0.70710678118654752f));
                T[wv][rl][in * 16 + l16] = v;
            }
        }
        asm volatile("s_waitcnt lgkmcnt(0)" ::: "memory");
        #pragma unroll
        for (int it = 0; it < 2; ++it) {
            const int flat = it * 256 + lane * 4;     // 0..508, 512 elements
            const int row = flat >> 5, col = flat & 31;
            const float4 vv = *(const float4*)&T[wv][row][col];
            const size_t oi = obase + (size_t)(wv * 96 + j * 16 + row) * 3136 + col;
            if (fp) {
                *(float4*)((float*)outp + oi) = vv;
            } else {
                const u32 a = (u32)f2bf(vv.x) | ((u32)f2bf(vv.y) << 16);
                const u32 b2 = (u32)f2bf(vv.z) | ((u32)f2bf(vv.w) << 16);
                *(uint2*)((u16*)outp + oi) = make_uint2(a, b2);
            }
        }
        asm volatile("s_waitcnt lgkmcnt(0)" ::: "memory");
    }
    #undef TRIP
    #undef SSTEP
    #undef LOADA
}

extern "C" void kernel_launch(void* const* d_in, const int* in_sizes, int n_in,
                              void* d_out, int out_size, void* d_ws, size_t ws_size,
                              hipStream_t stream) {
    const void* x   = d_in[0];
    const void* w   = d_in[1];
    const void* cbp = d_in[2];
    const void* bsc = d_in[3];
    const void* bbi = d_in[4];
    const void* bme = d_in[5];
    const void* bva = d_in[6];

    int* flag = (int*)d_ws;
    u16* xc   = (u16*)((char*)d_ws + 64);            // 77,070,336 B
    u16* wbf  = xc + (size_t)16 * 96 * 3136 * 8;     // 589,824 B

    detect_kernel<<<1, 64, 0, stream>>>((const u16*)x, flag);
    wconv_kernel<<<1152, 256, 0, stream>>>(w, wbf, flag);
    xj_kernel<<<dim3(48, 16), 256, 0, stream>>>(x, xc, flag);
    gemm_kernel<<<1568, 256, 0, stream>>>(xc, wbf, cbp, bsc, bbi, bme, bva,
                                          d_out, flag);
}

// Round 5
// 269.039 us; speedup vs baseline: 1.1853x; 1.1277x over previous
//
#include <hip/hip_runtime.h>
#include <cstdint>
#include <cstddef>

typedef unsigned short u16;
typedef unsigned int u32;
typedef __attribute__((ext_vector_type(8))) short short8;
typedef __attribute__((ext_vector_type(4))) float f32x4;

__device__ __forceinline__ float bf2f(u16 v) { return __uint_as_float((u32)v << 16); }
__device__ __forceinline__ u16 f2bf(float f) {
    u32 u = __float_as_uint(f);
    u = (u + 0x7fffu + ((u >> 16) & 1u)) >> 16;   // RNE, finite values only
    return (u16)u;
}

// async global->LDS, 16 B/lane; LDS dest must be wave-uniform base + lane*16
#define GLD16(g, l) __builtin_amdgcn_global_load_lds( \
    (const __attribute__((address_space(1))) void*)(g), \
    (__attribute__((address_space(3))) void*)(l), 16, 0, 0)

// ------------------------------------------------------------------
// Kernel 0: dtype sniffer (flag=1 -> fp32 inputs).
// ------------------------------------------------------------------
__global__ void detect_kernel(const u16* __restrict__ x, int* __restrict__ flag) {
    int cnt = 0;
    for (int i = threadIdx.x; i < 256; i += 64) {
        const int e = (x[2 * i] >> 7) & 0xFF;
        cnt += (e >= 96 && e <= 135) ? 1 : 0;
    }
    #pragma unroll
    for (int o = 32; o; o >>= 1) cnt += __shfl_down(cnt, o, 64);
    if (threadIdx.x == 0) *flag = (cnt < 128) ? 1 : 0;
}

// ------------------------------------------------------------------
// Kernel 1: W [384,768] -> bf16.
// ------------------------------------------------------------------
__global__ void wconv_kernel(const void* __restrict__ w, u16* __restrict__ wbf,
                             const int* __restrict__ flag) {
    const int i = blockIdx.x * 256 + threadIdx.x;
    if (i >= 384 * 768) return;
    if (*flag) wbf[i] = f2bf(((const float*)w)[i]);
    else       wbf[i] = ((const u16*)w)[i];
}

// ------------------------------------------------------------------
// Kernel 2: x_j stencil, pixel-major LDS [3136][8ch].
// v6: 512 threads (8 waves; LDS 50 KB -> 3 blocks/CU = 24 waves/CU,
// doubled latency hiding vs 256-thread version) + register-lean inner
// loop: per scale, 4 neighbor reads reduced with fminf pairs that fuse
// to v_min3_f32 (no off[20] array -> lower VGPR).
// xc layout: [b][group 0..95][hw][8c]; groups 0..47 = x, 48..95 = x_j.
// ------------------------------------------------------------------
__global__ __launch_bounds__(512) void xj_kernel(const void* __restrict__ xin,
                                                 u16* __restrict__ xc,
                                                 const int* __restrict__ flag) {
    const int cg = blockIdx.x, b = blockIdx.y;
    const int fp = *flag;
    __shared__ __align__(16) u16 pl[3136][8];
    const size_t plane0 = ((size_t)b * 384 + (size_t)cg * 8) * 3136;

    if (fp) {
        const float* xb = (const float*)xin + plane0;
        for (int g = threadIdx.x; g < 784; g += 512) {
            const int p = g * 4;
            float vv[8][4];
            #pragma unroll
            for (int c = 0; c < 8; ++c) {
                const float4 t = *(const float4*)(xb + (size_t)c * 3136 + p);
                vv[c][0] = t.x; vv[c][1] = t.y; vv[c][2] = t.z; vv[c][3] = t.w;
            }
            #pragma unroll
            for (int i = 0; i < 4; ++i) {
                u32 q[4];
                #pragma unroll
                for (int cc = 0; cc < 4; ++cc)
                    q[cc] = (u32)f2bf(vv[cc * 2][i]) | ((u32)f2bf(vv[cc * 2 + 1][i]) << 16);
                *(uint4*)&pl[p + i][0] = make_uint4(q[0], q[1], q[2], q[3]);
            }
        }
    } else {
        const u16* xb = (const u16*)xin + plane0;
        for (int g = threadIdx.x; g < 784; g += 512) {
            const int p = g * 4;
            u32 rc[8][2];
            #pragma unroll
            for (int c = 0; c < 8; ++c) {
                const uint2 t = *(const uint2*)(xb + (size_t)c * 3136 + p);
                rc[c][0] = t.x; rc[c][1] = t.y;
            }
            #pragma unroll
            for (int i = 0; i < 4; ++i) {
                const int d = i >> 1, sh = (i & 1) * 16;
                u32 q[4];
                #pragma unroll
                for (int cc = 0; cc < 4; ++cc) {
                    const u32 lo = (rc[cc * 2][d] >> sh) & 0xFFFFu;
                    const u32 hi = (rc[cc * 2 + 1][d] >> sh) & 0xFFFFu;
                    q[cc] = lo | (hi << 16);
                }
                *(uint4*)&pl[p + i][0] = make_uint4(q[0], q[1], q[2], q[3]);
            }
        }
    }
    __syncthreads();

    for (int p = threadIdx.x; p < 3136; p += 512) {
        const int h = p / 56, w = p - h * 56;
        const uint4 self = *(const uint4*)&pl[p][0];
        const u32 sw[4] = {self.x, self.y, self.z, self.w};
        float xv[8], mn[8];
        #pragma unroll
        for (int c2 = 0; c2 < 4; ++c2) {
            xv[c2 * 2]     = __uint_as_float(sw[c2] << 16);
            xv[c2 * 2 + 1] = __uint_as_float(sw[c2] & 0xFFFF0000u);
            mn[c2 * 2] = xv[c2 * 2]; mn[c2 * 2 + 1] = xv[c2 * 2 + 1];
        }
        const int S[5] = {1, 3, 7, 15, 31};
        #pragma unroll
        for (int si = 0; si < 5; ++si) {
            const int s = S[si];
            int hp = h + s; if (hp >= 56) hp -= 56;
            int hm = h - s; if (hm < 0)   hm += 56;
            int wp = w + s; if (wp >= 56) wp -= 56;
            int wm = w - s; if (wm < 0)   wm += 56;
            const uint4 n0 = *(const uint4*)&pl[hp * 56 + w][0];
            const uint4 n1 = *(const uint4*)&pl[hm * 56 + w][0];
            const uint4 n2 = *(const uint4*)&pl[h * 56 + wp][0];
            const uint4 n3 = *(const uint4*)&pl[h * 56 + wm][0];
            const u32 w0[4] = {n0.x, n0.y, n0.z, n0.w};
            const u32 w1[4] = {n1.x, n1.y, n1.z, n1.w};
            const u32 w2[4] = {n2.x, n2.y, n2.z, n2.w};
            const u32 w3[4] = {n3.x, n3.y, n3.z, n3.w};
            #pragma unroll
            for (int c2 = 0; c2 < 4; ++c2) {
                // low halves -> fminf pairs fuse to v_min3_f32
                mn[c2 * 2] = fminf(
                    fminf(__uint_as_float(w0[c2] << 16), __uint_as_float(w1[c2] << 16)),
                    fminf(fminf(__uint_as_float(w2[c2] << 16), __uint_as_float(w3[c2] << 16)),
                          mn[c2 * 2]));
                // high halves
                mn[c2 * 2 + 1] = fminf(
                    fminf(__uint_as_float(w0[c2] & 0xFFFF0000u), __uint_as_float(w1[c2] & 0xFFFF0000u)),
                    fminf(fminf(__uint_as_float(w2[c2] & 0xFFFF0000u), __uint_as_float(w3[c2] & 0xFFFF0000u)),
                          mn[c2 * 2 + 1]));
            }
        }
        u32 jq[4];
        #pragma unroll
        for (int c2 = 0; c2 < 4; ++c2)
            jq[c2] = (u32)f2bf(xv[c2 * 2] - mn[c2 * 2]) |
                     ((u32)f2bf(xv[c2 * 2 + 1] - mn[c2 * 2 + 1]) << 16);
        u16* px = xc + ((((size_t)b * 96) + cg) * 3136 + p) * 8;
        u16* pj = xc + ((((size_t)b * 96) + 48 + cg) * 3136 + p) * 8;
        *(uint4*)px = self;
        *(uint4*)pj = make_uint4(jq[0], jq[1], jq[2], jq[3]);
    }
}

// ------------------------------------------------------------------
// Kernel 3: Y = Wbf[384,768] @ Xc[768,50176] + BN + exact GELU.
// EXACT v0 restore (measured 110 us): barrier-light, A-fragments loaded
// straight from global (W is L2-hot), B double-buffered in LDS in 6
// phases of K=128. Tile M=192 x N=64; 4 waves, each 48x64 = 3x4 frags
// of mfma 16x16x32. grid (784, 2), block 256.
// ------------------------------------------------------------------
__global__ __launch_bounds__(256) void gemm_kernel(
        const u16* __restrict__ xc, const u16* __restrict__ Wt,
        const void* __restrict__ cb, const void* __restrict__ bsc,
        const void* __restrict__ bbi, const void* __restrict__ bme,
        const void* __restrict__ bva, void* __restrict__ outp,
        const int* __restrict__ flag) {
    const int ntile = blockIdx.x;             // 0..783
    const int mtile = blockIdx.y;             // 0..1
    const int fp = *flag;
    __shared__ __align__(16) u16 Bs[2][16 * 64 * 8];   // 2 x 16 KB (reused as T)
    __shared__ float2 PB[192];

    const int tid = threadIdx.x;
    if (tid < 192) {
        const int o = mtile * 192 + tid;
        float vsc, vva, vcb, vme, vbi;
        if (fp) {
            vsc = ((const float*)bsc)[o]; vva = ((const float*)bva)[o];
            vcb = ((const float*)cb)[o];  vme = ((const float*)bme)[o];
            vbi = ((const float*)bbi)[o];
        } else {
            vsc = bf2f(((const u16*)bsc)[o]); vva = bf2f(((const u16*)bva)[o]);
            vcb = bf2f(((const u16*)cb)[o]);  vme = bf2f(((const u16*)bme)[o]);
            vbi = bf2f(((const u16*)bbi)[o]);
        }
        const float seff = vsc * rsqrtf(vva + 1e-5f);
        PB[tid] = make_float2(seff, (vcb - vme) * seff + vbi);
    }

    const int lane = tid & 63, wv = tid >> 6;
    const int quad = lane >> 4, l16 = lane & 15;
    const int bb  = ntile / 49;
    const int hw0 = (ntile - bb * 49) * 64;

    // B staging: phase q covers groups q*16..+16; 1024 16B-chunks, 4/thread.
    const u16* bgp[4]; int bofs[4];
    #pragma unroll
    for (int i = 0; i < 4; ++i) {
        const int idx = i * 256 + tid;        // 0..1023
        const int gg = idx >> 6, n = idx & 63;
        bgp[i]  = xc + (((size_t)bb * 96 + gg) * 3136 + hw0 + n) * 8;
        bofs[i] = idx * 8;
    }
    #define STAGE(q) { \
        u16* dst = &Bs[(q) & 1][0]; \
        _Pragma("unroll") \
        for (int i = 0; i < 4; ++i) GLD16(bgp[i] + (size_t)(q) * 16 * 3136 * 8, dst + bofs[i]); }

    // A-fragment global pointers: row = mtile*192 + wv*48 + im*16 + l16
    const u16* arow[3];
    #pragma unroll
    for (int im = 0; im < 3; ++im)
        arow[im] = Wt + (size_t)(mtile * 192 + wv * 48 + im * 16 + l16) * 768 + quad * 8;

    f32x4 acc[3][4];
    #pragma unroll
    for (int im = 0; im < 3; ++im)
        #pragma unroll
        for (int in = 0; in < 4; ++in)
            acc[im][in] = {0.f, 0.f, 0.f, 0.f};

    STAGE(0);
    __syncthreads();                          // only full-latency drain

    for (int q = 0; q < 6; ++q) {
        if (q < 5) STAGE(q + 1);              // into other buffer, drains at end-of-phase barrier
        const u16* bufq = &Bs[q & 1][0];
        #pragma unroll
        for (int s = 0; s < 4; ++s) {
            const int k0 = q * 128 + s * 32;
            short8 af[3], bfv[4];
            #pragma unroll
            for (int im = 0; im < 3; ++im)
                af[im] = *(const short8*)(arow[im] + k0);
            #pragma unroll
            for (int in = 0; in < 4; ++in)
                bfv[in] = *(const short8*)(bufq + ((s * 4 + quad) * 64 + in * 16 + l16) * 8);
            #pragma unroll
            for (int im = 0; im < 3; ++im)
                #pragma unroll
                for (int in = 0; in < 4; ++in)
                    acc[im][in] = __builtin_amdgcn_mfma_f32_16x16x32_bf16(
                                      af[im], bfv[in], acc[im][in], 0, 0, 0);
        }
        __syncthreads();   // next-phase staging landed; buf[q&1] free for q+2
    }

    // --- epilogue: BN + exact GELU, per-wave LDS transpose, coalesced stores ---
    float* T = (float*)&Bs[0][0] + wv * (16 * 68);   // 4352 B/wave, disjoint
    const size_t obase = (size_t)bb * 384 * 3136 + hw0;
    #pragma unroll
    for (int im = 0; im < 3; ++im) {
        #pragma unroll
        for (int r = 0; r < 4; ++r) {
            const int ml = mtile * 192 + wv * 48 + im * 16 + quad * 4 + r;
            const float2 sb = PB[(wv * 48 + im * 16 + quad * 4 + r)];
            #pragma unroll
            for (int in = 0; in < 4; ++in) {
                float v = acc[im][in][r] * sb.x + sb.y;
                v = 0.5f * v * (1.0f + erff(v * 0.70710678118654752f));
                T[(quad * 4 + r) * 68 + in * 16 + l16] = v;
            }
            (void)ml;
        }
        asm volatile("s_waitcnt lgkmcnt(0)" ::: "memory");
        #pragma unroll
        for (int it = 0; it < 4; ++it) {
            const int flat = it * 256 + lane * 4;   // 0..1023
            const int row = flat >> 6, col = flat & 63;
            const float4 vv = *(const float4*)&T[row * 68 + col];
            const size_t oi = obase +
                (size_t)(mtile * 192 + wv * 48 + im * 16 + row) * 3136 + col;
            if (fp) {
                *(float4*)((float*)outp + oi) = vv;
            } else {
                const u32 a = (u32)f2bf(vv.x) | ((u32)f2bf(vv.y) << 16);
                const u32 b2 = (u32)f2bf(vv.z) | ((u32)f2bf(vv.w) << 16);
                *(uint2*)((u16*)outp + oi) = make_uint2(a, b2);
            }
        }
        asm volatile("s_waitcnt lgkmcnt(0)" ::: "memory");
    }
    #undef STAGE
}

extern "C" void kernel_launch(void* const* d_in, const int* in_sizes, int n_in,
                              void* d_out, int out_size, void* d_ws, size_t ws_size,
                              hipStream_t stream) {
    const void* x   = d_in[0];
    const void* w   = d_in[1];
    const void* cbp = d_in[2];
    const void* bsc = d_in[3];
    const void* bbi = d_in[4];
    const void* bme = d_in[5];
    const void* bva = d_in[6];

    int* flag = (int*)d_ws;
    u16* xc   = (u16*)((char*)d_ws + 64);            // 77,070,336 B
    u16* wbf  = xc + (size_t)16 * 96 * 3136 * 8;     // 589,824 B

    detect_kernel<<<1, 64, 0, stream>>>((const u16*)x, flag);
    wconv_kernel<<<1152, 256, 0, stream>>>(w, wbf, flag);
    xj_kernel<<<dim3(48, 16), 512, 0, stream>>>(x, xc, flag);
    gemm_kernel<<<dim3(784, 2), 256, 0, stream>>>(xc, wbf, cbp, bsc, bbi, bme, bva,
                                                  d_out, flag);
}

// Round 7
// 258.829 us; speedup vs baseline: 1.2320x; 1.0394x over previous
//
#include <hip/hip_runtime.h>
#include <cstdint>
#include <cstddef>

typedef unsigned short u16;
typedef unsigned int u32;
typedef __attribute__((ext_vector_type(8))) short short8;
typedef __attribute__((ext_vector_type(4))) float f32x4;

__device__ __forceinline__ float bf2f(u16 v) { return __uint_as_float((u32)v << 16); }
__device__ __forceinline__ u16 f2bf(float f) {
    u32 u = __float_as_uint(f);
    u = (u + 0x7fffu + ((u >> 16) & 1u)) >> 16;   // RNE, finite values only
    return (u16)u;
}

// async global->LDS, 16 B/lane; LDS dest must be wave-uniform base + lane*16
#define GLD16(g, l) __builtin_amdgcn_global_load_lds( \
    (const __attribute__((address_space(1))) void*)(g), \
    (__attribute__((address_space(3))) void*)(l), 16, 0, 0)

// ------------------------------------------------------------------
// Per-block dtype sniff (replaces detect_kernel; bit-identical flag).
// Checks exponent field of x[2i], i=0..255; flag=1 -> fp32 inputs.
// All waves compute the same count redundantly via 64-lane ballots.
// ------------------------------------------------------------------
__device__ __forceinline__ int sniff_fp(const void* x) {
    const u16* xs = (const u16*)x;
    const int lane = threadIdx.x & 63;
    int cnt = 0;
    #pragma unroll
    for (int k = 0; k < 4; ++k) {
        const int i = lane * 4 + k;                // i in 0..255, each once
        const int e = (xs[2 * i] >> 7) & 0xFF;
        cnt += (int)__popcll(__ballot(e >= 96 && e <= 135));
    }
    return (cnt < 128) ? 1 : 0;
}

// ------------------------------------------------------------------
// Kernel 1 (prep): fused W-convert + x_j stencil, self-detecting.
// grid (50, 16): cg 0..47 = xj blocks (one 8-ch group each),
// cg 48..49 = W[384,768]->bf16 conversion blocks.
// xc layout: [b][group 0..95][hw][8c]; groups 0..47 = x, 48..95 = x_j.
// ------------------------------------------------------------------
__global__ __launch_bounds__(512) void prep_kernel(const void* __restrict__ xin,
                                                   const void* __restrict__ w,
                                                   u16* __restrict__ xc,
                                                   u16* __restrict__ wbf) {
    const int cg = blockIdx.x, b = blockIdx.y;
    const int fp = sniff_fp(xin);

    if (cg >= 48) {
        // ---- wconv part: 32 blocks x 512 threads x 18 iters = 294912 elems
        const int base = ((cg - 48) * 16 + b) * 512 + threadIdx.x;
        for (int i = base; i < 384 * 768; i += 32 * 512) {
            if (fp) wbf[i] = f2bf(((const float*)w)[i]);
            else    wbf[i] = ((const u16*)w)[i];
        }
        return;
    }

    __shared__ __align__(16) u16 pl[3136][8];
    const size_t plane0 = ((size_t)b * 384 + (size_t)cg * 8) * 3136;

    if (fp) {
        const float* xb = (const float*)xin + plane0;
        for (int g = threadIdx.x; g < 784; g += 512) {
            const int p = g * 4;
            float vv[8][4];
            #pragma unroll
            for (int c = 0; c < 8; ++c) {
                const float4 t = *(const float4*)(xb + (size_t)c * 3136 + p);
                vv[c][0] = t.x; vv[c][1] = t.y; vv[c][2] = t.z; vv[c][3] = t.w;
            }
            #pragma unroll
            for (int i = 0; i < 4; ++i) {
                u32 q[4];
                #pragma unroll
                for (int cc = 0; cc < 4; ++cc)
                    q[cc] = (u32)f2bf(vv[cc * 2][i]) | ((u32)f2bf(vv[cc * 2 + 1][i]) << 16);
                *(uint4*)&pl[p + i][0] = make_uint4(q[0], q[1], q[2], q[3]);
            }
        }
    } else {
        const u16* xb = (const u16*)xin + plane0;
        for (int g = threadIdx.x; g < 784; g += 512) {
            const int p = g * 4;
            u32 rc[8][2];
            #pragma unroll
            for (int c = 0; c < 8; ++c) {
                const uint2 t = *(const uint2*)(xb + (size_t)c * 3136 + p);
                rc[c][0] = t.x; rc[c][1] = t.y;
            }
            #pragma unroll
            for (int i = 0; i < 4; ++i) {
                const int d = i >> 1, sh = (i & 1) * 16;
                u32 q[4];
                #pragma unroll
                for (int cc = 0; cc < 4; ++cc) {
                    const u32 lo = (rc[cc * 2][d] >> sh) & 0xFFFFu;
                    const u32 hi = (rc[cc * 2 + 1][d] >> sh) & 0xFFFFu;
                    q[cc] = lo | (hi << 16);
                }
                *(uint4*)&pl[p + i][0] = make_uint4(q[0], q[1], q[2], q[3]);
            }
        }
    }
    __syncthreads();

    for (int p = threadIdx.x; p < 3136; p += 512) {
        const int h = p / 56, w2 = p - h * 56;
        const uint4 self = *(const uint4*)&pl[p][0];
        const u32 sw[4] = {self.x, self.y, self.z, self.w};
        float xv[8], mn[8];
        #pragma unroll
        for (int c2 = 0; c2 < 4; ++c2) {
            xv[c2 * 2]     = __uint_as_float(sw[c2] << 16);
            xv[c2 * 2 + 1] = __uint_as_float(sw[c2] & 0xFFFF0000u);
            mn[c2 * 2] = xv[c2 * 2]; mn[c2 * 2 + 1] = xv[c2 * 2 + 1];
        }
        const int S[5] = {1, 3, 7, 15, 31};
        #pragma unroll
        for (int si = 0; si < 5; ++si) {
            const int s = S[si];
            int hp = h + s; if (hp >= 56) hp -= 56;
            int hm = h - s; if (hm < 0)   hm += 56;
            int wp = w2 + s; if (wp >= 56) wp -= 56;
            int wm = w2 - s; if (wm < 0)   wm += 56;
            const uint4 n0 = *(const uint4*)&pl[hp * 56 + w2][0];
            const uint4 n1 = *(const uint4*)&pl[hm * 56 + w2][0];
            const uint4 n2 = *(const uint4*)&pl[h * 56 + wp][0];
            const uint4 n3 = *(const uint4*)&pl[h * 56 + wm][0];
            const u32 w0[4] = {n0.x, n0.y, n0.z, n0.w};
            const u32 w1[4] = {n1.x, n1.y, n1.z, n1.w};
            const u32 wA[4] = {n2.x, n2.y, n2.z, n2.w};
            const u32 wB[4] = {n3.x, n3.y, n3.z, n3.w};
            #pragma unroll
            for (int c2 = 0; c2 < 4; ++c2) {
                mn[c2 * 2] = fminf(
                    fminf(__uint_as_float(w0[c2] << 16), __uint_as_float(w1[c2] << 16)),
                    fminf(fminf(__uint_as_float(wA[c2] << 16), __uint_as_float(wB[c2] << 16)),
                          mn[c2 * 2]));
                mn[c2 * 2 + 1] = fminf(
                    fminf(__uint_as_float(w0[c2] & 0xFFFF0000u), __uint_as_float(w1[c2] & 0xFFFF0000u)),
                    fminf(fminf(__uint_as_float(wA[c2] & 0xFFFF0000u), __uint_as_float(wB[c2] & 0xFFFF0000u)),
                          mn[c2 * 2 + 1]));
            }
        }
        u32 jq[4];
        #pragma unroll
        for (int c2 = 0; c2 < 4; ++c2)
            jq[c2] = (u32)f2bf(xv[c2 * 2] - mn[c2 * 2]) |
                     ((u32)f2bf(xv[c2 * 2 + 1] - mn[c2 * 2 + 1]) << 16);
        u16* px = xc + ((((size_t)b * 96) + cg) * 3136 + p) * 8;
        u16* pj = xc + ((((size_t)b * 96) + 48 + cg) * 3136 + p) * 8;
        *(uint4*)px = self;
        *(uint4*)pj = make_uint4(jq[0], jq[1], jq[2], jq[3]);
    }
}

// ------------------------------------------------------------------
// Kernel 2 (gemm): Y = Wbf[384,768] @ Xc[768,50176] + BN + exact GELU.
// v7 = the proven v0 structure with HALVED phase depth:
//   8 groups (K=64) per phase, 12 phases, Bs = 2 x 8 KB.
//   LDS 18944 B (smem 17408 union of Bs/T + PB 1536) -> 7 blocks/CU
//   capacity at VGPR=68 (28 waves/CU vs v0's 2.1 blocks measured).
//   All 6.1 blocks/CU of work resident -> barrier drains hidden by
//   other blocks. Everything else byte-identical to v0.
// Tile M=192 x N=64; 4 waves, each 48x64 = 3x4 frags of mfma 16x16x32.
// grid (784, 2), block 256. Self-detecting (no flag dependency).
// ------------------------------------------------------------------
__global__ __launch_bounds__(256) void gemm_kernel(
        const u16* __restrict__ xc, const u16* __restrict__ Wt,
        const void* __restrict__ cb, const void* __restrict__ bsc,
        const void* __restrict__ bbi, const void* __restrict__ bme,
        const void* __restrict__ bva, void* __restrict__ outp,
        const void* __restrict__ x0) {
    const int ntile = blockIdx.x;             // 0..783
    const int mtile = blockIdx.y;             // 0..1
    const int fp = sniff_fp(x0);
    // smem: 2 x 8 KB B buffers (16384 B), reused in epilogue as
    // 4 waves x 16x68 f32 transpose tiles (17408 B). PB separate.
    __shared__ __align__(16) unsigned char smem[17408];
    __shared__ float2 PB[192];
    u16* const Bsu = (u16*)smem;

    const int tid = threadIdx.x;
    if (tid < 192) {
        const int o = mtile * 192 + tid;
        float vsc, vva, vcb, vme, vbi;
        if (fp) {
            vsc = ((const float*)bsc)[o]; vva = ((const float*)bva)[o];
            vcb = ((const float*)cb)[o];  vme = ((const float*)bme)[o];
            vbi = ((const float*)bbi)[o];
        } else {
            vsc = bf2f(((const u16*)bsc)[o]); vva = bf2f(((const u16*)bva)[o]);
            vcb = bf2f(((const u16*)cb)[o]);  vme = bf2f(((const u16*)bme)[o]);
            vbi = bf2f(((const u16*)bbi)[o]);
        }
        const float seff = vsc * rsqrtf(vva + 1e-5f);
        PB[tid] = make_float2(seff, (vcb - vme) * seff + vbi);
    }

    const int lane = tid & 63, wv = tid >> 6;
    const int quad = lane >> 4, l16 = lane & 15;
    const int bb  = ntile / 49;
    const int hw0 = (ntile - bb * 49) * 64;

    // B staging: phase q covers groups q*8..+8; 512 16B-chunks, 2/thread.
    const u16* bgp[2]; int bofs[2];
    #pragma unroll
    for (int i = 0; i < 2; ++i) {
        const int idx = i * 256 + tid;        // 0..511
        const int gg = idx >> 6, n = idx & 63;
        bgp[i]  = xc + (((size_t)bb * 96 + gg) * 3136 + hw0 + n) * 8;
        bofs[i] = idx * 8;
    }
    #define STAGE(q) { \
        u16* dst = Bsu + ((q) & 1) * 4096; \
        _Pragma("unroll") \
        for (int i = 0; i < 2; ++i) GLD16(bgp[i] + (size_t)(q) * 8 * 3136 * 8, dst + bofs[i]); }

    // A-fragment global pointers: row = mtile*192 + wv*48 + im*16 + l16
    const u16* arow[3];
    #pragma unroll
    for (int im = 0; im < 3; ++im)
        arow[im] = Wt + (size_t)(mtile * 192 + wv * 48 + im * 16 + l16) * 768 + quad * 8;

    f32x4 acc[3][4];
    #pragma unroll
    for (int im = 0; im < 3; ++im)
        #pragma unroll
        for (int in = 0; in < 4; ++in)
            acc[im][in] = {0.f, 0.f, 0.f, 0.f};

    STAGE(0);
    __syncthreads();                          // only full-latency drain

    for (int q = 0; q < 12; ++q) {
        if (q < 11) STAGE(q + 1);             // into other buffer, drains at end-of-phase barrier
        const u16* bufq = Bsu + (q & 1) * 4096;
        #pragma unroll
        for (int s = 0; s < 2; ++s) {
            const int k0 = q * 64 + s * 32;
            short8 af[3], bfv[4];
            #pragma unroll
            for (int im = 0; im < 3; ++im)
                af[im] = *(const short8*)(arow[im] + k0);
            #pragma unroll
            for (int in = 0; in < 4; ++in)
                bfv[in] = *(const short8*)(bufq + ((s * 4 + quad) * 64 + in * 16 + l16) * 8);
            #pragma unroll
            for (int im = 0; im < 3; ++im)
                #pragma unroll
                for (int in = 0; in < 4; ++in)
                    acc[im][in] = __builtin_amdgcn_mfma_f32_16x16x32_bf16(
                                      af[im], bfv[in], acc[im][in], 0, 0, 0);
        }
        __syncthreads();   // next-phase staging landed; buf[q&1] free for q+2
    }

    // --- epilogue: BN + exact GELU, per-wave LDS transpose, coalesced stores ---
    float* T = (float*)smem + wv * (16 * 68);   // 4352 B/wave, disjoint
    const size_t obase = (size_t)bb * 384 * 3136 + hw0;
    #pragma unroll
    for (int im = 0; im < 3; ++im) {
        #pragma unroll
        for (int r = 0; r < 4; ++r) {
            const float2 sb = PB[(wv * 48 + im * 16 + quad * 4 + r)];
            #pragma unroll
            for (int in = 0; in < 4; ++in) {
                float v = acc[im][in][r] * sb.x + sb.y;
                v = 0.5f * v * (1.0f + erff(v * 0.70710678118654752f));
                T[(quad * 4 + r) * 68 + in * 16 + l16] = v;
            }
        }
        asm volatile("s_waitcnt lgkmcnt(0)" ::: "memory");
        #pragma unroll
        for (int it = 0; it < 4; ++it) {
            const int flat = it * 256 + lane * 4;   // 0..1023
            const int row = flat >> 6, col = flat & 63;
            const float4 vv = *(const float4*)&T[row * 68 + col];
            const size_t oi = obase +
                (size_t)(mtile * 192 + wv * 48 + im * 16 + row) * 3136 + col;
            if (fp) {
                *(float4*)((float*)outp + oi) = vv;
            } else {
                const u32 a = (u32)f2bf(vv.x) | ((u32)f2bf(vv.y) << 16);
                const u32 b2 = (u32)f2bf(vv.z) | ((u32)f2bf(vv.w) << 16);
                *(uint2*)((u16*)outp + oi) = make_uint2(a, b2);
            }
        }
        asm volatile("s_waitcnt lgkmcnt(0)" ::: "memory");
    }
    #undef STAGE
}

extern "C" void kernel_launch(void* const* d_in, const int* in_sizes, int n_in,
                              void* d_out, int out_size, void* d_ws, size_t ws_size,
                              hipStream_t stream) {
    const void* x   = d_in[0];
    const void* w   = d_in[1];
    const void* cbp = d_in[2];
    const void* bsc = d_in[3];
    const void* bbi = d_in[4];
    const void* bme = d_in[5];
    const void* bva = d_in[6];

    u16* xc   = (u16*)((char*)d_ws + 64);            // 77,070,336 B
    u16* wbf  = xc + (size_t)16 * 96 * 3136 * 8;     // 589,824 B

    prep_kernel<<<dim3(50, 16), 512, 0, stream>>>(x, w, xc, wbf);
    gemm_kernel<<<dim3(784, 2), 256, 0, stream>>>(xc, wbf, cbp, bsc, bbi, bme, bva,
                                                  d_out, x);
}